// Round 1
// baseline (376.516 us; speedup 1.0000x reference)
//
#include <hip/hip_runtime.h>

#define BB 512
#define SS 1024
#define TT 64

__device__ __forceinline__ float wsum64(float v) {
#pragma unroll
  for (int off = 32; off > 0; off >>= 1) v += __shfl_xor(v, off, 64);
  return v;
}

// X-macro list: apply M(i) for i = 0..63
#define E_LIST(M) \
  M(0) M(1) M(2) M(3) M(4) M(5) M(6) M(7) \
  M(8) M(9) M(10) M(11) M(12) M(13) M(14) M(15) \
  M(16) M(17) M(18) M(19) M(20) M(21) M(22) M(23) \
  M(24) M(25) M(26) M(27) M(28) M(29) M(30) M(31) \
  M(32) M(33) M(34) M(35) M(36) M(37) M(38) M(39) \
  M(40) M(41) M(42) M(43) M(44) M(45) M(46) M(47) \
  M(48) M(49) M(50) M(51) M(52) M(53) M(54) M(55) \
  M(56) M(57) M(58) M(59) M(60) M(61) M(62) M(63)

#define RLF(v, i) __int_as_float(__builtin_amdgcn_readlane(__float_as_int(v), (i)))

// 16 uniform-address (broadcast) LDS quad loads: 64 broadcast values, 16 instrs.
#define LOAD_ALLQ                                                     \
  float4 q0 = pshv[0], q1 = pshv[1], q2 = pshv[2], q3 = pshv[3];      \
  float4 q4 = pshv[4], q5 = pshv[5], q6 = pshv[6], q7 = pshv[7];      \
  float4 q8 = pshv[8], q9 = pshv[9], q10 = pshv[10], q11 = pshv[11];  \
  float4 q12 = pshv[12], q13 = pshv[13], q14 = pshv[14], q15 = pshv[15];

#define FMAQ(qq, eA, eB, eC, eD) \
  a0 = fmaf((qq).x, eA, a0);     \
  a1 = fmaf((qq).y, eB, a1);     \
  a2 = fmaf((qq).z, eC, a2);     \
  a3 = fmaf((qq).w, eD, a3);

#define FMA_ALLQ                     \
  FMAQ(q0, E0, E1, E2, E3)           \
  FMAQ(q1, E4, E5, E6, E7)           \
  FMAQ(q2, E8, E9, E10, E11)         \
  FMAQ(q3, E12, E13, E14, E15)       \
  FMAQ(q4, E16, E17, E18, E19)       \
  FMAQ(q5, E20, E21, E22, E23)       \
  FMAQ(q6, E24, E25, E26, E27)       \
  FMAQ(q7, E28, E29, E30, E31)       \
  FMAQ(q8, E32, E33, E34, E35)       \
  FMAQ(q9, E36, E37, E38, E39)       \
  FMAQ(q10, E40, E41, E42, E43)      \
  FMAQ(q11, E44, E45, E46, E47)      \
  FMAQ(q12, E48, E49, E50, E51)      \
  FMAQ(q13, E52, E53, E54, E55)      \
  FMAQ(q14, E56, E57, E58, E59)      \
  FMAQ(q15, E60, E61, E62, E63)

// Forward step (identical math to previous verified version; broadcast via LDS):
// s_j = sum_i p_i E_ij ; p' = s * (f * inv); write p' for next step's broadcast.
#define CRF_STEP_FWD(ev, mkv)                                                       \
  do {                                                                              \
    LOAD_ALLQ                                                                       \
    float f_ = __expf((ev) * (mkv));                                                \
    float fi_ = f_ * inv;                                                           \
    float a0 = 0.f, a1 = 0.f, a2 = 0.f, a3 = 0.f;                                   \
    FMA_ALLQ                                                                        \
    float s_ = (a0 + a1) + (a2 + a3);                                               \
    p = s_ * fi_;                                                                   \
    psh[lane] = p;                                                                  \
    float rn_ = __int_as_float(__builtin_amdgcn_readfirstlane(__float_as_int(s_))); \
    inv = __builtin_amdgcn_rcpf(rn_);                                               \
    float lg_ = __logf(rn_);                                                        \
    Lacc += lg_;                                                                    \
    lastlg = lg_;                                                                   \
  } while (0)

// Backward step: LDS holds w_t = p_{t-1} * f_t (written by the previous
// iteration). Compute s_i = sum_j E_ij w_j ; p = s * inv (scale moved to the
// output side so readfirstlane/rcp stay off the write path); then write
// w_{t+1} = p * f_{t+1} using the one-step-ahead emission (env/mknv).
// Applied-inverse accounting is identical to the input-side version.
#define CRF_STEP_BWD(env, mknv)                                                     \
  do {                                                                              \
    LOAD_ALLQ                                                                       \
    float fn_ = __expf((env) * (mknv));                                             \
    float a0 = 0.f, a1 = 0.f, a2 = 0.f, a3 = 0.f;                                   \
    FMA_ALLQ                                                                        \
    float s_ = (a0 + a1) + (a2 + a3);                                               \
    p = s_ * inv;                                                                   \
    psh[lane] = p * fn_;                                                            \
    float rn_ = __int_as_float(__builtin_amdgcn_readfirstlane(__float_as_int(s_))); \
    inv = __builtin_amdgcn_rcpf(rn_);                                               \
    float lg_ = __logf(rn_);                                                        \
    Lacc += lg_;                                                                    \
    lastlg = lg_;                                                                   \
  } while (0)

template <int DIR>
__device__ __forceinline__ void part_run(int b, int lane, const float* __restrict__ em,
                                         const float* __restrict__ mask,
                                         const float* __restrict__ trans,
                                         float* __restrict__ outv) {
  __shared__ float4 pshv[TT / 4];  // per-block broadcast buffer (one wave/block)
  float* psh = (float*)pshv;

  // Per-lane E fragment as 64 NAMED scalars (never an array -> never scratch).
  // fwd lane j holds column E[i][j]; bwd lane i holds row E[i][j].
  const float* tp = trans + (DIR == 0 ? lane : lane * TT);
#define EINIT(i) float E##i = __expf((DIR == 0) ? tp[(i)*TT] : tp[(i)]);
  E_LIST(EINIT)
#undef EINIT

  const float* emb = em + (size_t)b * SS * TT;
  const float* mkb = mask + (size_t)b * SS;

  constexpr int NST = (DIR == 0) ? (SS / 2 - 1) : (SS / 2);  // 511 fwd, 512 bwd
  constexpr int S0 = (DIR == 0) ? 1 : (SS - 1);
  constexpr int SD = (DIR == 0) ? 1 : -1;
  constexpr int NG8 = NST / 8;    // full groups of 8 steps
  constexpr int TAIL8 = NST & 7;  // 7 fwd, 0 bwd

  float p, inv = 1.0f, Lacc = 0.0f, lastlg = 0.0f;

  // 8-deep emission prefetch (coalesced: lane j reads em[b][s][j])
  float ebuf[8];
#pragma unroll
  for (int k = 0; k < 8; ++k) ebuf[k] = emb[(S0 + SD * k) * TT + lane];
  const float* ep = emb + (ptrdiff_t)(S0 + SD * 8) * TT + lane;

  // mask: one coalesced vector load per 64 steps, broadcast via readlane
  float mv = mkb[S0 + SD * lane];  // window 0 (steps 0..63 of this run)

  if (DIR == 0) {
    p = __expf(emb[lane] * mkb[0]);
    psh[lane] = p;  // broadcast for step 1
  } else {
    p = 1.0f;
    float mk1 = RLF(mv, 0);
    float f1 = __expf(ebuf[0] * mk1);
    psh[lane] = f1;  // w_1 = p_0 * f_1 = f_1
  }

  for (int t8 = 0; t8 < NG8; ++t8) {
    if (DIR == 0 && (t8 & 7) == 0) mv = mkb[S0 + SD * (t8 * 8 + lane)];
    const int base = (t8 & 7) * 8;
#pragma unroll
    for (int k = 0; k < 8; ++k) {
      float e = ebuf[k];
      ebuf[k] = *ep;  // prefetch step t+8; always in-bounds (fwd s<=519, bwd s>=504)
      ep += SD * TT;
      if (DIR == 0) {
        float mk = RLF(mv, base + k);
        CRF_STEP_FWD(e, mk);
      } else {
        // one-step-ahead emission/mask for the w_{t+1} write
        float mk_next;
        if (base + k == 63) {  // next step starts a new 64-step mask window
          mv = mkb[S0 + SD * (t8 * 8 + 8 + lane)];
          mk_next = RLF(mv, 0);
        } else {
          mk_next = RLF(mv, base + k + 1);
        }
        float e_next = ebuf[(k + 1) & 7];
        CRF_STEP_BWD(e_next, mk_next);
      }
    }
  }
  if constexpr (TAIL8 > 0) {  // fwd only
#pragma unroll
    for (int k = 0; k < TAIL8; ++k) {
      float e = ebuf[k];
      float mk = RLF(mv, (NG8 & 7) * 8 + k);
      CRF_STEP_FWD(e, mk);
    }
  }

  outv[b * TT + lane] = __logf(p) + (Lacc - lastlg);
}

// Fused: blocks [0, 1024) = partition fwd/bwd; blocks [1024, 3072) = gold score
__global__ void __launch_bounds__(64, 1)
    fused_kernel(const float* __restrict__ em, const int* __restrict__ tags,
                 const float* __restrict__ mask, const float* __restrict__ trans,
                 float* __restrict__ alpha, float* __restrict__ beta,
                 float* __restrict__ gpart) {
  const int lane = threadIdx.x;
  const int bid = blockIdx.x;
  if (bid < 2 * BB) {
    const int b = bid >> 1;
    if ((bid & 1) == 0)
      part_run<0>(b, lane, em, mask, trans, alpha);
    else
      part_run<1>(b, lane, em, mask, trans, beta);
  } else {
    const int gid = bid - 2 * BB;  // 0..2047
    const int b = gid >> 2, q = gid & 3;
    const int* tg = tags + b * SS;
    const float* mkb = mask + (size_t)b * SS;
    const float* emb = em + (size_t)b * SS * TT;
    float part = 0.f;
#pragma unroll
    for (int i = 0; i < 4; ++i) {
      int s = q * 256 + i * 64 + lane;
      int t1 = tg[s];
      float e = emb[s * TT + t1];
      float contrib = (s == 0) ? e : (trans[t1 * TT + tg[s - 1]] + e);
      part = fmaf(contrib, mkb[s], part);
    }
    part = wsum64(part);
    if (lane == 0) gpart[gid] = part;
  }
}

// Single block, 512 threads: thread b computes Z_b - gold_b, block-reduces, writes mean.
__global__ void combine_kernel(const float* __restrict__ alpha, const float* __restrict__ beta,
                               const float* __restrict__ gpart, float* __restrict__ out) {
  const int b = threadIdx.x;  // 0..511
  const float* av = alpha + b * TT;
  const float* bv = beta + b * TT;
  float m = -3.4e38f, s = 0.f;
#pragma unroll 8
  for (int j = 0; j < TT; ++j) {
    float v = av[j] + bv[j];
    float nm = fmaxf(m, v);
    s = s * __expf(m - nm) + __expf(v - nm);
    m = nm;
  }
  float Z = m + __logf(s);
  float g = gpart[4 * b] + gpart[4 * b + 1] + gpart[4 * b + 2] + gpart[4 * b + 3];
  float val = Z - g;
  val = wsum64(val);
  __shared__ float red[8];
  if ((threadIdx.x & 63) == 0) red[threadIdx.x >> 6] = val;
  __syncthreads();
  if (threadIdx.x == 0) {
    float t = 0.f;
#pragma unroll
    for (int w = 0; w < 8; ++w) t += red[w];
    out[0] = t * (1.0f / (float)BB);
  }
}

extern "C" void kernel_launch(void* const* d_in, const int* in_sizes, int n_in,
                              void* d_out, int out_size, void* d_ws, size_t ws_size,
                              hipStream_t stream) {
  const float* em = (const float*)d_in[0];
  const int* tags = (const int*)d_in[1];
  const float* mask = (const float*)d_in[2];
  const float* trans = (const float*)d_in[3];
  float* out = (float*)d_out;

  float* alpha = (float*)d_ws;      // 512*64
  float* beta = alpha + BB * TT;    // 512*64
  float* gpart = beta + BB * TT;    // 2048

  fused_kernel<<<2 * BB + 4 * BB, TT, 0, stream>>>(em, tags, mask, trans, alpha, beta, gpart);
  combine_kernel<<<1, BB, 0, stream>>>(alpha, beta, gpart, out);
}